// Round 10
// baseline (1800.150 us; speedup 1.0000x reference)
//
#include <hip/hip_runtime.h>
#include <hip/hip_bf16.h>

typedef short bf16x8 __attribute__((ext_vector_type(8)));
typedef float f32x4 __attribute__((ext_vector_type(4)));

#define LOG2E 1.4426950408889634f

__device__ __forceinline__ float fexp(float x){ return __builtin_amdgcn_exp2f(x * LOG2E); }
__device__ __forceinline__ float frcp(float x){ return __builtin_amdgcn_rcpf(x); }
__device__ __forceinline__ float tanh_fast(float x){ float e = fexp(2.f*x); return 1.f - 2.f*frcp(e + 1.f); }
__device__ __forceinline__ float sigm_fast(float x){ return frcp(1.f + fexp(-x)); }
__device__ __forceinline__ float elu_fast(float x){ return x > 0.f ? x : fexp(x) - 1.f; }
__device__ __forceinline__ float dot4(float4 a, float4 b){
  return (a.x*b.x + a.y*b.y) + (a.z*b.z + a.w*b.w);
}
__device__ __forceinline__ float wsum(float v){
  #pragma unroll
  for (int o = 32; o > 0; o >>= 1) v += __shfl_xor(v, o, 64);
  return v;
}
__device__ __forceinline__ unsigned pk2(float a, float b){
  unsigned lo = __bfloat16_as_ushort(__float2bfloat16(a));
  unsigned hi = __bfloat16_as_ushort(__float2bfloat16(b));
  return lo | (hi << 16);
}
__device__ __forceinline__ float bflo(unsigned u){ return __uint_as_float(u << 16); }
__device__ __forceinline__ float bfhi(unsigned u){ return __uint_as_float(u & 0xffff0000u); }
__device__ __forceinline__ unsigned short bfq(float a){
  return __bfloat16_as_ushort(__float2bfloat16(a));
}

// A-fragment LDS tile: [kt][lanep][8 bf16] with XOR swizzle.
__device__ __forceinline__ int afrag_off(int kt, int lanep){
  int off = (kt << 10) + (lanep << 4);
  off ^= ((lanep >> 4) & 1) << 5;
  off ^= (kt & 1) << 6;
  return off;
}

// ---------------------------------------------------------------------------
// K0: pack B-operand MFMA fragments (bf16) for the 3 GEMMs + bio.
// ---------------------------------------------------------------------------
__global__ void k_prep(const float* __restrict__ FC1_w, const float* __restrict__ W_hh,
                       const float* __restrict__ FCout1_w,
                       const float* __restrict__ b_ih, const float* __restrict__ b_hh,
                       unsigned short* __restrict__ B1f, unsigned short* __restrict__ B2f,
                       unsigned short* __restrict__ B3f, float* __restrict__ bio)
{
  int n = blockIdx.x * 256 + threadIdx.x;
  if (n < 32768) {              // B1: Wds (K=256, N=128), NT=8 KT=8
    int jj = n & 7, lane = (n >> 3) & 63, ktn = n >> 9;
    int kt = ktn & 7, nt = ktn >> 3;
    int nn = nt*16 + (lane & 15), k = kt*32 + ((lane >> 4) << 3) + jj;
    B1f[n] = bfq(FC1_w[nn*384 + k]);
  } else if (n < 98304) {       // B2: Whh (K=128, N=512), NT=32 KT=4
    int n2 = n - 32768;
    int jj = n2 & 7, lane = (n2 >> 3) & 63, ktn = n2 >> 9;
    int kt = ktn & 3, nt = ktn >> 2;
    int nn = nt*16 + (lane & 15), k = kt*32 + ((lane >> 4) << 3) + jj;
    B2f[n2] = bfq(W_hh[nn*128 + k]);
  } else if (n < 131072) {      // B3: Fo1 (K=256, N=128), NT=8 KT=8
    int n3 = n - 98304;
    int jj = n3 & 7, lane = (n3 >> 3) & 63, ktn = n3 >> 9;
    int kt = ktn & 7, nt = ktn >> 3;
    int nn = nt*16 + (lane & 15), k = kt*32 + ((lane >> 4) << 3) + jj;
    B3f[n3] = bfq(FCout1_w[nn*256 + k]);
  } else if (n < 131584) {
    int n4 = n - 131072;
    bio[n4] = b_ih[n4] + b_hh[n4];
  }
}

// ---------------------------------------------------------------------------
// K1: HWp[b][m4][t]{4 bf16} = FC1_w[m][256+k].H[b][t][k] + FC1_b[m];
//     P[b][t] = sum_k H[b][t][k] * FCin_w[1+k];  H->bf16 (Hbf).
// ---------------------------------------------------------------------------
__global__ __launch_bounds__(256) void k_hw(
    const float* __restrict__ H, const float* __restrict__ FC1_w,
    const float* __restrict__ FC1_b, const float* __restrict__ FCin_w,
    unsigned short* __restrict__ HWp, float* __restrict__ P,
    unsigned short* __restrict__ Hbf)
{
  __shared__ __align__(16) float Hl[64][128];
  const int b = blockIdx.x, tid = threadIdx.x;
  const float* Hb = H + (size_t)b * 8192;
  for (int i = tid; i < 8192; i += 256) ((float*)Hl)[i] = Hb[i];
  __syncthreads();

  if (Hbf) {
    unsigned* Ho = (unsigned*)Hbf + (size_t)b * 4096;
    for (int i = tid; i < 4096; i += 256) {
      float2 v = ((const float2*)Hl)[i];
      Ho[i] = pk2(v.x, v.y);
    }
  }
  if (tid < 64) {   // P[b][t]
    float acc = 0.f;
    #pragma unroll 8
    for (int k4 = 0; k4 < 32; ++k4) {
      float4 h = *(const float4*)&Hl[tid][4*k4];
      float4 f = *(const float4*)&FCin_w[1 + 4*k4];
      acc += dot4(h, f);
    }
    P[(size_t)b*64 + tid] = acc;
  }

  const int m = tid >> 1, t0 = (tid & 1) * 32;
  float acc[32];
  const float bias = FC1_b[m];
  #pragma unroll
  for (int j = 0; j < 32; ++j) acc[j] = bias;

  const float* wrow = FC1_w + m*384 + 256;
  for (int k4 = 0; k4 < 32; ++k4) {
    float4 w = *(const float4*)(wrow + 4*k4);
    #pragma unroll
    for (int j = 0; j < 32; ++j) {
      float4 h = *(const float4*)&Hl[t0 + j][4*k4];
      acc[j] += dot4(w, h);
    }
  }
  unsigned short* o = HWp + (((size_t)b*32 + (m >> 2))*64 + t0)*4 + (m & 3);
  #pragma unroll
  for (int j = 0; j < 32; ++j)
    o[j*4] = bfq(acc[j]);
}

// ---------------------------------------------------------------------------
// K2: recurrence, R3 structure (3 barriers/step, out-GEMM in its own phase).
// Persistent regs: wA(32) + wO(32) + hwreg(64, the step-invariant HW row) --
// gate weights wG are STREAMED from XCD-L2 each step instead. Net regs equal
// to R3 (~244/wave, 2 waves/SIMD, no spills), but the logit pass runs from
// registers instead of re-fetching 16KB/step from L3.
// ---------------------------------------------------------------------------
template<bool HB>
__global__ __launch_bounds__(512, 2) void k_main(
    const float* __restrict__ Hf_, const float* __restrict__ Y,
    const unsigned short* __restrict__ HWp, const unsigned short* __restrict__ Hbf,
    const unsigned short* __restrict__ B1f, const unsigned short* __restrict__ B2f,
    const unsigned short* __restrict__ B3f, const float* __restrict__ bio,
    const float* __restrict__ FC2_w, const float* __restrict__ Pg,
    const float* __restrict__ FCin_w, const float* __restrict__ FCin_b,
    const float* __restrict__ W_ih,
    const float* __restrict__ FCout1_b, const float* __restrict__ FCout2_w,
    const float* __restrict__ FCout2_b, float* __restrict__ out, int L)
{
  __shared__ __align__(16) char  AFds[8192];      // A-frags [d|s] bf16 (K=256)
  __shared__ __align__(16) char  AFdc[8192];      // A-frags [d|C] bf16 (K=256)
  __shared__ __align__(16) float a_l[8][128];
  __shared__ __align__(16) float ho_l[8][128];
  __shared__ __align__(16) float gate_l[8][512];
  __shared__ __align__(16) float alpha_l[8][64];
  __shared__ __align__(16) float y_l[8][64];
  __shared__ __align__(16) float fc2s[128], fo2s[128], fo1bs[128], fcinC[128];
  __shared__ __align__(16) float bios[512], wihs[512];
  __shared__ float scal[4];

  const int tid = threadIdx.x, w = tid >> 6, lane = tid & 63;

  if (tid < 128) {
    fc2s[tid] = FC2_w[tid]; fo2s[tid] = FCout2_w[tid];
    fo1bs[tid] = FCout1_b[tid]; fcinC[tid] = FCin_w[1 + tid];
  }
  bios[tid] = bio[tid];
  wihs[tid] = W_ih[tid];
  y_l[tid >> 6][tid & 63] = Y[((size_t)(blockIdx.x*8 + (tid >> 6)))*64 + (tid & 63)];
  if (tid == 0) { scal[0] = FCin_b[0]; scal[1] = FCout2_b[0]; scal[2] = FCin_w[0]; }
  #pragma unroll
  for (int i = 0; i < 4; ++i) {
    ((int*)AFds)[tid*4 + i] = 0;
    ((int*)AFdc)[tid*4 + i] = 0;
  }
  __syncthreads();

  // persistent weight fragments: wA, wO only (wG streamed per step)
  const bf16x8* B1v = (const bf16x8*)B1f;
  const bf16x8* B2v = (const bf16x8*)B2f;
  const bf16x8* B3v = (const bf16x8*)B3f;
  bf16x8 wA[8], wO[8];
  #pragma unroll
  for (int kt = 0; kt < 8; ++kt) wA[kt] = B1v[(w*8 + kt)*64 + lane];
  #pragma unroll
  for (int kt = 0; kt < 8; ++kt) wO[kt] = B3v[(w*8 + kt)*64 + lane];
  const int b2base = w*1024 + lane;   // + (t2*4+kt)*64

  const int b = blockIdx.x * 8 + w;
  const unsigned* Hbu = (const unsigned*)Hbf + (size_t)b * 4096;
  const float2* Hf2 = (const float2*)(Hf_ + (size_t)b * 8192);

  // step-invariant HW row, held in registers for all 64 steps
  const uint2* HWu = (const uint2*)HWp + (size_t)b * 2048;
  uint2 hwreg[32];
  #pragma unroll
  for (int m4 = 0; m4 < 32; ++m4) hwreg[m4] = HWu[m4*64 + lane];

  float2 sst = {0.f, 0.f};                 // cell state for j=2*lane, 2*lane+1
  const int drow = (lane >> 4) * 4;
  const bool dvalid = (lane < 32);
  const int ncb = lane & 15;
  const int j = lane << 1;
  // publish coords for k=j (d) and k=128+j (s / C)
  const int p_g = (j >> 3) & 3, p_bo = (j & 7) * 2;
  const int p_off   = afrag_off(j >> 5,       w + 16*p_g) + p_bo;
  const int p_off_s = afrag_off(4 + (j >> 5), w + 16*p_g) + p_bo;

  for (int step = 0; step < L; ++step) {
    // ---------- Phase A': a-GEMM + gates-GEMM (wG streamed) ----------
    bf16x8 af[8];
    #pragma unroll
    for (int kt = 0; kt < 8; ++kt) af[kt] = *(const bf16x8*)&AFds[afrag_off(kt, lane)];
    f32x4 accA = {0.f,0.f,0.f,0.f};
    #pragma unroll
    for (int kt = 0; kt < 8; ++kt)
      accA = __builtin_amdgcn_mfma_f32_16x16x32_bf16(af[kt], wA[kt], accA, 0, 0, 0);
    f32x4 aG[4];
    #pragma unroll
    for (int t2 = 0; t2 < 4; ++t2) {
      bf16x8 g0 = B2v[b2base + (t2*4 + 0)*64];
      bf16x8 g1 = B2v[b2base + (t2*4 + 1)*64];
      bf16x8 g2 = B2v[b2base + (t2*4 + 2)*64];
      bf16x8 g3 = B2v[b2base + (t2*4 + 3)*64];
      f32x4 acc = {0.f,0.f,0.f,0.f};
      acc = __builtin_amdgcn_mfma_f32_16x16x32_bf16(af[0], g0, acc, 0, 0, 0);
      acc = __builtin_amdgcn_mfma_f32_16x16x32_bf16(af[1], g1, acc, 0, 0, 0);
      acc = __builtin_amdgcn_mfma_f32_16x16x32_bf16(af[2], g2, acc, 0, 0, 0);
      acc = __builtin_amdgcn_mfma_f32_16x16x32_bf16(af[3], g3, acc, 0, 0, 0);
      aG[t2] = acc;
    }
    if (dvalid) {
      int nc = w*16 + ncb;
      #pragma unroll
      for (int r2 = 0; r2 < 4; ++r2) a_l[drow + r2][nc] = accA[r2];
      #pragma unroll
      for (int t2 = 0; t2 < 4; ++t2) {
        int ng = (w*4 + t2)*16 + ncb;
        #pragma unroll
        for (int r2 = 0; r2 < 4; ++r2) gate_l[drow + r2][ng] = aG[t2][r2];
      }
    }
    __syncthreads();   // S1

    // ---------- Phase B (wave w = row w): logits from registers ----------
    float lg0 = 0.f, lg1 = 0.f;
    #pragma unroll
    for (int m4 = 0; m4 < 32; ++m4) {
      uint2 u = hwreg[m4];
      float4 av = *(const float4*)&a_l[w][m4*4];
      float4 fv = *(const float4*)&fc2s[m4*4];
      lg0 += fv.x * tanh_fast(av.x + bflo(u.x));
      lg1 += fv.y * tanh_fast(av.y + bfhi(u.x));
      lg0 += fv.z * tanh_fast(av.z + bflo(u.y));
      lg1 += fv.w * tanh_fast(av.w + bfhi(u.y));
    }
    float lg = lg0 + lg1;

    float ex = fexp(lg);                    // |lg| <= ~11: no max-sub needed
    float alpha = ex * frcp(wsum(ex));
    alpha_l[w][lane] = alpha;

    float cx = 0.f, cy = 0.f;
    #pragma unroll 4
    for (int t4 = 0; t4 < 16; ++t4) {
      float4 av = *(const float4*)&alpha_l[w][t4*4];
      if (HB) {
        unsigned h0 = Hbu[(t4*4 + 0)*64 + lane];
        unsigned h1 = Hbu[(t4*4 + 1)*64 + lane];
        unsigned h2 = Hbu[(t4*4 + 2)*64 + lane];
        unsigned h3 = Hbu[(t4*4 + 3)*64 + lane];
        cx += av.x*bflo(h0); cy += av.x*bfhi(h0);
        cx += av.y*bflo(h1); cy += av.y*bfhi(h1);
        cx += av.z*bflo(h2); cy += av.z*bfhi(h2);
        cx += av.w*bflo(h3); cy += av.w*bfhi(h3);
      } else {
        float2 h0 = Hf2[(t4*4 + 0)*64 + lane];
        float2 h1 = Hf2[(t4*4 + 1)*64 + lane];
        float2 h2 = Hf2[(t4*4 + 2)*64 + lane];
        float2 h3 = Hf2[(t4*4 + 3)*64 + lane];
        cx += av.x*h0.x; cy += av.x*h0.y;
        cx += av.y*h1.x; cy += av.y*h1.y;
        cx += av.z*h2.x; cy += av.z*h2.y;
        cx += av.w*h3.x; cy += av.w*h3.y;
      }
    }

    float2 fcv = *(const float2*)&fcinC[j];
    float part = wsum(fcv.x*cx + fcv.y*cy);
    float yt = y_l[w][step];
    float li = part + scal[2]*yt + scal[0];

    float2 gi = *(const float2*)&gate_l[w][j];
    float2 gf = *(const float2*)&gate_l[w][128 + j];
    float2 gg = *(const float2*)&gate_l[w][256 + j];
    float2 go = *(const float2*)&gate_l[w][384 + j];
    float2 wv, bv;
    wv = *(const float2*)&wihs[j];       bv = *(const float2*)&bios[j];
    gi.x += li*wv.x + bv.x; gi.y += li*wv.y + bv.y;
    wv = *(const float2*)&wihs[128 + j]; bv = *(const float2*)&bios[128 + j];
    gf.x += li*wv.x + bv.x; gf.y += li*wv.y + bv.y;
    wv = *(const float2*)&wihs[256 + j]; bv = *(const float2*)&bios[256 + j];
    gg.x += li*wv.x + bv.x; gg.y += li*wv.y + bv.y;
    wv = *(const float2*)&wihs[384 + j]; bv = *(const float2*)&bios[384 + j];
    go.x += li*wv.x + bv.x; go.y += li*wv.y + bv.y;

    sst.x = sigm_fast(gf.x)*sst.x + sigm_fast(gi.x)*tanh_fast(gg.x);
    sst.y = sigm_fast(gf.y)*sst.y + sigm_fast(gi.y)*tanh_fast(gg.y);
    float dx = sigm_fast(go.x)*tanh_fast(sst.x);
    float dy = sigm_fast(go.y)*tanh_fast(sst.y);

    unsigned dp = pk2(dx, dy), sp = pk2(sst.x, sst.y), cp = pk2(cx, cy);
    *(unsigned*)&AFds[p_off]   = dp;
    *(unsigned*)&AFdc[p_off]   = dp;
    *(unsigned*)&AFds[p_off_s] = sp;
    *(unsigned*)&AFdc[p_off_s] = cp;
    __syncthreads();   // S2

    // ---------- Phase C: out-GEMM ----------
    f32x4 accO = {0.f,0.f,0.f,0.f};
    #pragma unroll
    for (int kt = 0; kt < 8; ++kt) {
      bf16x8 afc = *(const bf16x8*)&AFdc[afrag_off(kt, lane)];
      accO = __builtin_amdgcn_mfma_f32_16x16x32_bf16(afc, wO[kt], accO, 0, 0, 0);
    }
    if (dvalid) {
      int nc = w*16 + ncb;
      #pragma unroll
      for (int r2 = 0; r2 < 4; ++r2) ho_l[drow + r2][nc] = accO[r2];
    }
    __syncthreads();   // S3

    // ---------- Phase D: elu + FCout2 reduction ----------
    float2 hv = *(const float2*)&ho_l[w][j];
    float2 bb = *(const float2*)&fo1bs[j];
    float e0 = elu_fast(hv.x + bb.x), e1 = elu_fast(hv.y + bb.y);
    float2 fv2 = *(const float2*)&fo2s[j];
    float op = wsum(fv2.x*e0 + fv2.y*e1);
    if (lane == 0) out[(size_t)b*L + step] = op + scal[1];
  }
}

extern "C" void kernel_launch(void* const* d_in, const int* in_sizes, int n_in,
                              void* d_out, int out_size, void* d_ws, size_t ws_size,
                              hipStream_t stream) {
  const float* H        = (const float*)d_in[0];
  const float* y        = (const float*)d_in[1];
  const float* FC1_w    = (const float*)d_in[2];
  const float* FC1_b    = (const float*)d_in[3];
  const float* FC2_w    = (const float*)d_in[4];
  // d_in[5] = FC2_b (softmax-invariant, unused)
  const float* FCin_w   = (const float*)d_in[6];
  const float* FCin_b   = (const float*)d_in[7];
  const float* W_ih     = (const float*)d_in[8];
  const float* W_hh     = (const float*)d_in[9];
  const float* b_ih     = (const float*)d_in[10];
  const float* b_hh     = (const float*)d_in[11];
  const float* FCout1_w = (const float*)d_in[12];
  const float* FCout1_b = (const float*)d_in[13];
  const float* FCout2_w = (const float*)d_in[14];
  const float* FCout2_b = (const float*)d_in[15];
  float* out = (float*)d_out;
  const int L = out_size / 2048;   // target_length (= 64)

  char* ws = (char*)d_ws;
  unsigned short* B1f = (unsigned short*)(ws + 0);        //  64 KB
  unsigned short* B2f = (unsigned short*)(ws + 65536);    // 128 KB
  unsigned short* B3f = (unsigned short*)(ws + 196608);   //  64 KB
  float*          bio = (float*)(ws + 262144);            //   2 KB
  float*          P   = (float*)(ws + 264192);            // 512 KB
  unsigned short* HWp = (unsigned short*)(ws + 788480);   //  32 MB
  unsigned short* Hbf = (unsigned short*)(ws + 788480 + 33554432);  // 32 MB
  const bool hb = ws_size >= (size_t)(788480 + 2*33554432);

  k_prep<<<514, 256, 0, stream>>>(FC1_w, W_hh, FCout1_w, b_ih, b_hh,
                                  B1f, B2f, B3f, bio);
  k_hw<<<2048, 256, 0, stream>>>(H, FC1_w, FC1_b, FCin_w, HWp, P,
                                 hb ? Hbf : nullptr);
  if (hb)
    k_main<true><<<256, 512, 0, stream>>>(H, y, HWp, Hbf, B1f, B2f, B3f, bio,
                                          FC2_w, P, FCin_w, FCin_b, W_ih,
                                          FCout1_b, FCout2_w, FCout2_b, out, L);
  else
    k_main<false><<<256, 512, 0, stream>>>(H, y, HWp, Hbf, B1f, B2f, B3f, bio,
                                           FC2_w, P, FCin_w, FCin_b, W_ih,
                                           FCout1_b, FCout2_w, FCout2_b, out, L);
}

// Round 11
// 1260.822 us; speedup vs baseline: 1.4278x; 1.4278x over previous
//
#include <hip/hip_runtime.h>
#include <hip/hip_bf16.h>

typedef short bf16x8 __attribute__((ext_vector_type(8)));
typedef float f32x4 __attribute__((ext_vector_type(4)));

#define LOG2E 1.4426950408889634f

__device__ __forceinline__ float fexp(float x){ return __builtin_amdgcn_exp2f(x * LOG2E); }
__device__ __forceinline__ float frcp(float x){ return __builtin_amdgcn_rcpf(x); }
__device__ __forceinline__ float tanh_fast(float x){ float e = fexp(2.f*x); return 1.f - 2.f*frcp(e + 1.f); }
__device__ __forceinline__ float sigm_fast(float x){ return frcp(1.f + fexp(-x)); }
__device__ __forceinline__ float elu_fast(float x){ return x > 0.f ? x : fexp(x) - 1.f; }
__device__ __forceinline__ float dot4(float4 a, float4 b){
  return (a.x*b.x + a.y*b.y) + (a.z*b.z + a.w*b.w);
}
__device__ __forceinline__ float wsum(float v){
  #pragma unroll
  for (int o = 32; o > 0; o >>= 1) v += __shfl_xor(v, o, 64);
  return v;
}
__device__ __forceinline__ unsigned pk2(float a, float b){
  unsigned lo = __bfloat16_as_ushort(__float2bfloat16(a));
  unsigned hi = __bfloat16_as_ushort(__float2bfloat16(b));
  return lo | (hi << 16);
}
__device__ __forceinline__ float bflo(unsigned u){ return __uint_as_float(u << 16); }
__device__ __forceinline__ float bfhi(unsigned u){ return __uint_as_float(u & 0xffff0000u); }
__device__ __forceinline__ unsigned short bfq(float a){
  return __bfloat16_as_ushort(__float2bfloat16(a));
}

// A-fragment LDS tile: [kt][lanep][8 bf16] with XOR swizzle.
__device__ __forceinline__ int afrag_off(int kt, int lanep){
  int off = (kt << 10) + (lanep << 4);
  off ^= ((lanep >> 4) & 1) << 5;
  off ^= (kt & 1) << 6;
  return off;
}

// ---------------------------------------------------------------------------
// K0: pack B-operand MFMA fragments (bf16) for the 3 GEMMs + bio.
// ---------------------------------------------------------------------------
__global__ void k_prep(const float* __restrict__ FC1_w, const float* __restrict__ W_hh,
                       const float* __restrict__ FCout1_w,
                       const float* __restrict__ b_ih, const float* __restrict__ b_hh,
                       unsigned short* __restrict__ B1f, unsigned short* __restrict__ B2f,
                       unsigned short* __restrict__ B3f, float* __restrict__ bio)
{
  int n = blockIdx.x * 256 + threadIdx.x;
  if (n < 32768) {              // B1: Wds (K=256, N=128), NT=8 KT=8
    int jj = n & 7, lane = (n >> 3) & 63, ktn = n >> 9;
    int kt = ktn & 7, nt = ktn >> 3;
    int nn = nt*16 + (lane & 15), k = kt*32 + ((lane >> 4) << 3) + jj;
    B1f[n] = bfq(FC1_w[nn*384 + k]);
  } else if (n < 98304) {       // B2: Whh (K=128, N=512), NT=32 KT=4
    int n2 = n - 32768;
    int jj = n2 & 7, lane = (n2 >> 3) & 63, ktn = n2 >> 9;
    int kt = ktn & 3, nt = ktn >> 2;
    int nn = nt*16 + (lane & 15), k = kt*32 + ((lane >> 4) << 3) + jj;
    B2f[n2] = bfq(W_hh[nn*128 + k]);
  } else if (n < 131072) {      // B3: Fo1 (K=256, N=128), NT=8 KT=8
    int n3 = n - 98304;
    int jj = n3 & 7, lane = (n3 >> 3) & 63, ktn = n3 >> 9;
    int kt = ktn & 7, nt = ktn >> 3;
    int nn = nt*16 + (lane & 15), k = kt*32 + ((lane >> 4) << 3) + jj;
    B3f[n3] = bfq(FCout1_w[nn*256 + k]);
  } else if (n < 131584) {
    int n4 = n - 131072;
    bio[n4] = b_ih[n4] + b_hh[n4];
  }
}

// ---------------------------------------------------------------------------
// K1: HWp[b][m4][t]{4 bf16} = FC1_w[m][256+k].H[b][t][k] + FC1_b[m];
//     P[b][t] = sum_k H[b][t][k]*FCin_w[1+k];
//     Hbt[b][pair p][t] = packed bf16 pair (transposed for vectorized C-loop).
// ---------------------------------------------------------------------------
__global__ __launch_bounds__(256) void k_hw(
    const float* __restrict__ H, const float* __restrict__ FC1_w,
    const float* __restrict__ FC1_b, const float* __restrict__ FCin_w,
    unsigned short* __restrict__ HWp, float* __restrict__ P,
    unsigned short* __restrict__ Hbt)
{
  __shared__ __align__(16) float Hl[64][128];
  const int b = blockIdx.x, tid = threadIdx.x;
  const float* Hb = H + (size_t)b * 8192;
  for (int i = tid; i < 8192; i += 256) ((float*)Hl)[i] = Hb[i];
  __syncthreads();

  if (Hbt) {
    unsigned* Ho = (unsigned*)Hbt + (size_t)b * 4096;
    for (int i = tid; i < 4096; i += 256) {      // i = t*64 + p
      float2 v = ((const float2*)Hl)[i];
      Ho[(i & 63)*64 + (i >> 6)] = pk2(v.x, v.y);   // [p][t]
    }
  }
  if (tid < 64) {   // P[b][t]
    float acc = 0.f;
    #pragma unroll 8
    for (int k4 = 0; k4 < 32; ++k4) {
      float4 h = *(const float4*)&Hl[tid][4*k4];
      float4 f = *(const float4*)&FCin_w[1 + 4*k4];
      acc += dot4(h, f);
    }
    P[(size_t)b*64 + tid] = acc;
  }

  const int m = tid >> 1, t0 = (tid & 1) * 32;
  float acc[32];
  const float bias = FC1_b[m];
  #pragma unroll
  for (int j = 0; j < 32; ++j) acc[j] = bias;

  const float* wrow = FC1_w + m*384 + 256;
  for (int k4 = 0; k4 < 32; ++k4) {
    float4 w = *(const float4*)(wrow + 4*k4);
    #pragma unroll
    for (int j = 0; j < 32; ++j) {
      float4 h = *(const float4*)&Hl[t0 + j][4*k4];
      acc[j] += dot4(w, h);
    }
  }
  unsigned short* o = HWp + (((size_t)b*32 + (m >> 2))*64 + t0)*4 + (m & 3);
  #pragma unroll
  for (int j = 0; j < 32; ++j)
    o[j*4] = bfq(acc[j]);
}

// ---------------------------------------------------------------------------
// K2: recurrence — exact R3 structure (8 waves = 8 rows, all weights
// persistent, 3 barriers/step) + P-trick (gates independent of C) +
// vectorized C-loads (Hbt transposed, dwordx4) + deeper logit unroll.
// ---------------------------------------------------------------------------
template<bool HB>
__global__ __launch_bounds__(512, 2) void k_main(
    const float* __restrict__ Hf_, const float* __restrict__ Y,
    const unsigned short* __restrict__ HWp, const unsigned short* __restrict__ Hbt,
    const unsigned short* __restrict__ B1f, const unsigned short* __restrict__ B2f,
    const unsigned short* __restrict__ B3f, const float* __restrict__ bio,
    const float* __restrict__ FC2_w, const float* __restrict__ Pg,
    const float* __restrict__ FCin_w, const float* __restrict__ FCin_b,
    const float* __restrict__ W_ih,
    const float* __restrict__ FCout1_b, const float* __restrict__ FCout2_w,
    const float* __restrict__ FCout2_b, float* __restrict__ out, int L)
{
  __shared__ __align__(16) char  AFds[8192];      // A-frags [d|s] bf16 (K=256)
  __shared__ __align__(16) char  AFdc[8192];      // A-frags [d|C] bf16 (K=256)
  __shared__ __align__(16) float a_l[8][128];
  __shared__ __align__(16) float ho_l[8][128];
  __shared__ __align__(16) float gate_l[8][512];
  __shared__ __align__(16) float alpha_l[8][64];
  __shared__ __align__(16) float y_l[8][64];
  __shared__ __align__(16) float fc2s[128], fo2s[128], fo1bs[128];
  __shared__ __align__(16) float bios[512], wihs[512];
  __shared__ float scal[4];

  const int tid = threadIdx.x, w = tid >> 6, lane = tid & 63;

  if (tid < 128) {
    fc2s[tid] = FC2_w[tid]; fo2s[tid] = FCout2_w[tid];
    fo1bs[tid] = FCout1_b[tid];
  }
  bios[tid] = bio[tid];
  wihs[tid] = W_ih[tid];
  y_l[tid >> 6][tid & 63] = Y[((size_t)(blockIdx.x*8 + (tid >> 6)))*64 + (tid & 63)];
  if (tid == 0) { scal[0] = FCin_b[0]; scal[1] = FCout2_b[0]; scal[2] = FCin_w[0]; }
  #pragma unroll
  for (int i = 0; i < 4; ++i) {
    ((int*)AFds)[tid*4 + i] = 0;
    ((int*)AFdc)[tid*4 + i] = 0;
  }
  __syncthreads();

  // persistent weight fragments (128 dw, held across all steps)
  const bf16x8* B1v = (const bf16x8*)B1f;
  const bf16x8* B2v = (const bf16x8*)B2f;
  const bf16x8* B3v = (const bf16x8*)B3f;
  bf16x8 wA[8], wG[4][4], wO[8];
  #pragma unroll
  for (int kt = 0; kt < 8; ++kt) wA[kt] = B1v[(w*8 + kt)*64 + lane];
  #pragma unroll
  for (int t2 = 0; t2 < 4; ++t2)
    #pragma unroll
    for (int kt = 0; kt < 4; ++kt) wG[t2][kt] = B2v[((w*4 + t2)*4 + kt)*64 + lane];
  #pragma unroll
  for (int kt = 0; kt < 8; ++kt) wO[kt] = B3v[(w*8 + kt)*64 + lane];

  const int b = blockIdx.x * 8 + w;
  const uint2* HWu = (const uint2*)HWp + (size_t)b * 2048;
  const uint4* Hbt4 = (const uint4*)((const unsigned*)Hbt + (size_t)b * 4096 + lane*64);
  const float2* Hf2 = (const float2*)(Hf_ + (size_t)b * 8192);
  const float pP = Pg[(size_t)b*64 + lane];    // P[b][t=lane], step-invariant

  float2 sst = {0.f, 0.f};                 // cell state for j=2*lane, 2*lane+1
  const int drow = (lane >> 4) * 4;
  const bool dvalid = (lane < 32);
  const int ncb = lane & 15;
  const int j = lane << 1;
  // publish coords for k=j (d) and k=128+j (s / C)
  const int p_g = (j >> 3) & 3, p_bo = (j & 7) * 2;
  const int p_off   = afrag_off(j >> 5,       w + 16*p_g) + p_bo;
  const int p_off_s = afrag_off(4 + (j >> 5), w + 16*p_g) + p_bo;

  for (int step = 0; step < L; ++step) {
    // ---------- Phase A': a-GEMM + gates-GEMM (read AFds = prev d,s) ----------
    bf16x8 af[8];
    #pragma unroll
    for (int kt = 0; kt < 8; ++kt) af[kt] = *(const bf16x8*)&AFds[afrag_off(kt, lane)];
    f32x4 accA = {0.f,0.f,0.f,0.f};
    #pragma unroll
    for (int kt = 0; kt < 8; ++kt)
      accA = __builtin_amdgcn_mfma_f32_16x16x32_bf16(af[kt], wA[kt], accA, 0, 0, 0);
    f32x4 aG[4];
    #pragma unroll
    for (int t2 = 0; t2 < 4; ++t2) {
      f32x4 acc = {0.f,0.f,0.f,0.f};
      #pragma unroll
      for (int kt = 0; kt < 4; ++kt)
        acc = __builtin_amdgcn_mfma_f32_16x16x32_bf16(af[kt], wG[t2][kt], acc, 0, 0, 0);
      aG[t2] = acc;
    }
    if (dvalid) {
      int nc = w*16 + ncb;
      #pragma unroll
      for (int r2 = 0; r2 < 4; ++r2) a_l[drow + r2][nc] = accA[r2];
      #pragma unroll
      for (int t2 = 0; t2 < 4; ++t2) {
        int ng = (w*4 + t2)*16 + ncb;
        #pragma unroll
        for (int r2 = 0; r2 < 4; ++r2) gate_l[drow + r2][ng] = aG[t2][r2];
      }
    }
    __syncthreads();   // S1

    // ---------- Phase B (wave w = row w): logits (lane = t) ----------
    float lg0 = 0.f, lg1 = 0.f;
    #pragma unroll 8
    for (int m4 = 0; m4 < 32; ++m4) {
      uint2 u = HWu[m4*64 + lane];
      float4 av = *(const float4*)&a_l[w][m4*4];
      float4 fv = *(const float4*)&fc2s[m4*4];
      lg0 += fv.x * tanh_fast(av.x + bflo(u.x));
      lg1 += fv.y * tanh_fast(av.y + bfhi(u.x));
      lg0 += fv.z * tanh_fast(av.z + bflo(u.y));
      lg1 += fv.w * tanh_fast(av.w + bfhi(u.y));
    }
    float lg = lg0 + lg1;

    // ---------- softmax + li in one pass (P-trick; gates independent of C) ----
    float ex = fexp(lg);                    // |lg| <= ~11: no max-sub needed
    float se  = wsum(ex);
    float sep = wsum(ex * pP);
    float inv = frcp(se);
    float alpha = ex * inv;
    alpha_l[w][lane] = alpha;
    float yt = y_l[w][step];
    float li = sep * inv + scal[2]*yt + scal[0];

    // ---------- C (lane = pair j): vectorized dwordx4 loads; the load tail
    // overlaps the gate/LSTM compute below (no data dependence) ----------
    float cx = 0.f, cy = 0.f;
    #pragma unroll 4
    for (int t4 = 0; t4 < 16; ++t4) {
      float4 av = *(const float4*)&alpha_l[w][t4*4];
      if (HB) {
        uint4 hh = Hbt4[t4];
        cx += av.x*bflo(hh.x); cy += av.x*bfhi(hh.x);
        cx += av.y*bflo(hh.y); cy += av.y*bfhi(hh.y);
        cx += av.z*bflo(hh.z); cy += av.z*bfhi(hh.z);
        cx += av.w*bflo(hh.w); cy += av.w*bfhi(hh.w);
      } else {
        float2 h0 = Hf2[(t4*4 + 0)*64 + lane];
        float2 h1 = Hf2[(t4*4 + 1)*64 + lane];
        float2 h2 = Hf2[(t4*4 + 2)*64 + lane];
        float2 h3 = Hf2[(t4*4 + 3)*64 + lane];
        cx += av.x*h0.x; cy += av.x*h0.y;
        cx += av.y*h1.x; cy += av.y*h1.y;
        cx += av.z*h2.x; cy += av.z*h2.y;
        cx += av.w*h3.x; cy += av.w*h3.y;
      }
    }

    // ---------- gates + LSTM update ----------
    float2 gi = *(const float2*)&gate_l[w][j];
    float2 gf = *(const float2*)&gate_l[w][128 + j];
    float2 gg = *(const float2*)&gate_l[w][256 + j];
    float2 go = *(const float2*)&gate_l[w][384 + j];
    float2 wv, bv;
    wv = *(const float2*)&wihs[j];       bv = *(const float2*)&bios[j];
    gi.x += li*wv.x + bv.x; gi.y += li*wv.y + bv.y;
    wv = *(const float2*)&wihs[128 + j]; bv = *(const float2*)&bios[128 + j];
    gf.x += li*wv.x + bv.x; gf.y += li*wv.y + bv.y;
    wv = *(const float2*)&wihs[256 + j]; bv = *(const float2*)&bios[256 + j];
    gg.x += li*wv.x + bv.x; gg.y += li*wv.y + bv.y;
    wv = *(const float2*)&wihs[384 + j]; bv = *(const float2*)&bios[384 + j];
    go.x += li*wv.x + bv.x; go.y += li*wv.y + bv.y;

    sst.x = sigm_fast(gf.x)*sst.x + sigm_fast(gi.x)*tanh_fast(gg.x);
    sst.y = sigm_fast(gf.y)*sst.y + sigm_fast(gi.y)*tanh_fast(gg.y);
    float dx = sigm_fast(go.x)*tanh_fast(sst.x);
    float dy = sigm_fast(go.y)*tanh_fast(sst.y);

    unsigned dp = pk2(dx, dy), sp = pk2(sst.x, sst.y), cp = pk2(cx, cy);
    *(unsigned*)&AFds[p_off]   = dp;
    *(unsigned*)&AFdc[p_off]   = dp;
    *(unsigned*)&AFds[p_off_s] = sp;
    *(unsigned*)&AFdc[p_off_s] = cp;
    __syncthreads();   // S2

    // ---------- Phase C: out-GEMM ----------
    f32x4 accO = {0.f,0.f,0.f,0.f};
    #pragma unroll
    for (int kt = 0; kt < 8; ++kt) {
      bf16x8 afc = *(const bf16x8*)&AFdc[afrag_off(kt, lane)];
      accO = __builtin_amdgcn_mfma_f32_16x16x32_bf16(afc, wO[kt], accO, 0, 0, 0);
    }
    if (dvalid) {
      int nc = w*16 + ncb;
      #pragma unroll
      for (int r2 = 0; r2 < 4; ++r2) ho_l[drow + r2][nc] = accO[r2];
    }
    __syncthreads();   // S3

    // ---------- Phase D: elu + FCout2 reduction ----------
    float2 hv = *(const float2*)&ho_l[w][j];
    float2 bb = *(const float2*)&fo1bs[j];
    float e0 = elu_fast(hv.x + bb.x), e1 = elu_fast(hv.y + bb.y);
    float2 fv2 = *(const float2*)&fo2s[j];
    float op = wsum(fv2.x*e0 + fv2.y*e1);
    if (lane == 0) out[(size_t)b*L + step] = op + scal[1];
  }
}

extern "C" void kernel_launch(void* const* d_in, const int* in_sizes, int n_in,
                              void* d_out, int out_size, void* d_ws, size_t ws_size,
                              hipStream_t stream) {
  const float* H        = (const float*)d_in[0];
  const float* y        = (const float*)d_in[1];
  const float* FC1_w    = (const float*)d_in[2];
  const float* FC1_b    = (const float*)d_in[3];
  const float* FC2_w    = (const float*)d_in[4];
  // d_in[5] = FC2_b (softmax-invariant, unused)
  const float* FCin_w   = (const float*)d_in[6];
  const float* FCin_b   = (const float*)d_in[7];
  const float* W_ih     = (const float*)d_in[8];
  const float* W_hh     = (const float*)d_in[9];
  const float* b_ih     = (const float*)d_in[10];
  const float* b_hh     = (const float*)d_in[11];
  const float* FCout1_w = (const float*)d_in[12];
  const float* FCout1_b = (const float*)d_in[13];
  const float* FCout2_w = (const float*)d_in[14];
  const float* FCout2_b = (const float*)d_in[15];
  float* out = (float*)d_out;
  const int L = out_size / 2048;   // target_length (= 64)

  char* ws = (char*)d_ws;
  unsigned short* B1f = (unsigned short*)(ws + 0);        //  64 KB
  unsigned short* B2f = (unsigned short*)(ws + 65536);    // 128 KB
  unsigned short* B3f = (unsigned short*)(ws + 196608);   //  64 KB
  float*          bio = (float*)(ws + 262144);            //   2 KB
  float*          P   = (float*)(ws + 264192);            // 512 KB
  unsigned short* HWp = (unsigned short*)(ws + 788480);   //  32 MB
  unsigned short* Hbt = (unsigned short*)(ws + 788480 + 33554432);  // 32 MB
  const bool hb = ws_size >= (size_t)(788480 + 2*33554432);

  k_prep<<<514, 256, 0, stream>>>(FC1_w, W_hh, FCout1_w, b_ih, b_hh,
                                  B1f, B2f, B3f, bio);
  k_hw<<<2048, 256, 0, stream>>>(H, FC1_w, FC1_b, FCin_w, HWp, P,
                                 hb ? Hbt : nullptr);
  if (hb)
    k_main<true><<<256, 512, 0, stream>>>(H, y, HWp, Hbt, B1f, B2f, B3f, bio,
                                          FC2_w, P, FCin_w, FCin_b, W_ih,
                                          FCout1_b, FCout2_w, FCout2_b, out, L);
  else
    k_main<false><<<256, 512, 0, stream>>>(H, y, HWp, Hbt, B1f, B2f, B3f, bio,
                                           FC2_w, P, FCin_w, FCin_b, W_ih,
                                           FCout1_b, FCout2_w, FCout2_b, out, L);
}